// Round 1
// baseline (295.283 us; speedup 1.0000x reference)
//
#include <hip/hip_runtime.h>
#include <math.h>

// Shift_11261404250938: per-image shift(±10% trunc) + zero-fill, then
// standardize + min-max normalize. Standardization cancels algebraically in
// the min-max step, so output = (shifted - min) / (max - min).
// One block per image: phase-1 min/max reduction, phase-2 normalize+store.

constexpr int kC = 3, kH = 224, kW = 224;
constexpr int kHW  = kH * kW;        // 50176
constexpr int kCHW = kC * kHW;       // 150528
constexpr int kROWS = kC * kH;       // 672
constexpr int kQPR  = kW / 4;        // 56 float4 per row
constexpr int kNQ   = kROWS * kQPR;  // 37632 quads per image
constexpr int BLOCK = 1024;

__global__ __launch_bounds__(BLOCK) void shift_norm(
    const float* __restrict__ x, const float* __restrict__ sfy,
    const float* __restrict__ sfx, float* __restrict__ out)
{
    const int img = blockIdx.x;
    const float* __restrict__ xb = x + (size_t)img * kCHW;
    float* __restrict__ ob = out + (size_t)img * kCHW;

    // Replicate reference fp32 order: ((f*2-1)*0.1f)*size, trunc toward zero.
    float ty = sfy[img] * 2.0f - 1.0f; ty *= 0.1f; ty *= (float)kH;
    const int sy = (int)truncf(ty);
    float tx = sfx[img] * 2.0f - 1.0f; tx *= 0.1f; tx *= (float)kW;
    const int sx = (int)truncf(tx);

    const int tid = threadIdx.x;
    float vmin = INFINITY, vmax = -INFINITY;

    // Phase 1: min/max over the shifted image (masked positions contribute 0,
    // exactly like the reference's zero-fill).
    for (int f = tid; f < kNQ; f += BLOCK) {
        const int r = f / kQPR;            // row in [0, C*H)
        const int q = f - r * kQPR;
        const int j = r % kH;              // row within channel
        const int jj = j + sy;
        const bool rowok = (unsigned)jj < (unsigned)kH;
        const float* src = xb + (r - j + jj) * kW;  // c*H*W + jj*W
        const int i0 = q * 4;
        #pragma unroll
        for (int k = 0; k < 4; ++k) {
            const int ii = i0 + k + sx;
            float v = 0.0f;
            if (rowok && (unsigned)ii < (unsigned)kW) v = src[ii];
            vmin = fminf(vmin, v);
            vmax = fmaxf(vmax, v);
        }
    }

    // Wave (64-lane) shuffle reduction, then cross-wave via LDS.
    #pragma unroll
    for (int off = 32; off > 0; off >>= 1) {
        vmin = fminf(vmin, __shfl_down(vmin, off));
        vmax = fmaxf(vmax, __shfl_down(vmax, off));
    }
    __shared__ float smin[BLOCK / 64], smax[BLOCK / 64];
    __shared__ float s_mn, s_inv;
    const int wave = tid >> 6, lane = tid & 63;
    if (lane == 0) { smin[wave] = vmin; smax[wave] = vmax; }
    __syncthreads();
    if (tid == 0) {
        float mn = smin[0], mx = smax[0];
        #pragma unroll
        for (int w2 = 1; w2 < BLOCK / 64; ++w2) {
            mn = fminf(mn, smin[w2]);
            mx = fmaxf(mx, smax[w2]);
        }
        s_mn = mn;
        s_inv = 1.0f / (mx - mn);
    }
    __syncthreads();
    const float mn = s_mn, inv = s_inv;

    // Phase 2: recompute shifted value (hits L2/L3) and store normalized.
    for (int f = tid; f < kNQ; f += BLOCK) {
        const int r = f / kQPR;
        const int q = f - r * kQPR;
        const int j = r % kH;
        const int jj = j + sy;
        const bool rowok = (unsigned)jj < (unsigned)kH;
        const float* src = xb + (r - j + jj) * kW;
        const int i0 = q * 4;
        float4 o;
        float* po = (float*)&o;
        #pragma unroll
        for (int k = 0; k < 4; ++k) {
            const int ii = i0 + k + sx;
            float v = 0.0f;
            if (rowok && (unsigned)ii < (unsigned)kW) v = src[ii];
            po[k] = (v - mn) * inv;
        }
        *(float4*)(ob + r * kW + i0) = o;  // i0 % 4 == 0 -> 16B aligned
    }
}

extern "C" void kernel_launch(void* const* d_in, const int* in_sizes, int n_in,
                              void* d_out, int out_size, void* d_ws, size_t ws_size,
                              hipStream_t stream) {
    const float* x  = (const float*)d_in[0];
    const float* fy = (const float*)d_in[1];
    const float* fx = (const float*)d_in[2];
    float* out = (float*)d_out;
    const int B = in_sizes[1];  // shift_fy has one element per image
    shift_norm<<<B, BLOCK, 0, stream>>>(x, fy, fx, out);
}

// Round 2
// 293.843 us; speedup vs baseline: 1.0049x; 1.0049x over previous
//
#include <hip/hip_runtime.h>
#include <math.h>

// Shift_11261404250938: per-image shift(trunc(±10%)) + zero-fill, standardize,
// min-max normalize. Standardization cancels in the min-max step, so
// out = (shifted - min) / (max - min).
//
// R1 -> R2: both phases rewritten branch-free with aligned float4 loads.
//  - Phase 1: min/max over the valid input sub-rect; invalid elems -> 0 via
//    cndmask (correct: invalid region nonempty <=> zero-fill exists).
//  - Phase 2: misaligned-by-sx gather done as two aligned float4 loads + a
//    wave-uniform rotate (template on sx&3), clamped bases (clamped lanes are
//    always masked), per-element validity cndmask, aligned float4 store.

constexpr int kC = 3, kH = 224, kW = 224;
constexpr int kCHW = kC * kH * kW;   // 150528
constexpr int kROWS = kC * kH;       // 672
constexpr int kQPR  = kW / 4;        // 56 quads per row
constexpr int kNQ   = kROWS * kQPR;  // 37632 quads per image
constexpr int BLOCK = 1024;

template <int R>
__device__ __forceinline__ void phase2(const float* __restrict__ xb,
                                       float* __restrict__ ob,
                                       int sy, int sx, float mn, float inv,
                                       int tid)
{
    for (int f = tid; f < kNQ; f += BLOCK) {
        const int rr = f / kQPR;           // row in [0, C*H)
        const int q  = f - rr * kQPR;
        const int j  = rr % kH;            // row within channel
        const int c0 = rr - j;             // c * kH
        const int jj = j + sy;
        const bool rowok = (unsigned)jj < (unsigned)kH;
        const int jc = rowok ? jj : 0;     // clamp (masked anyway)
        const float* __restrict__ src = xb + (c0 + jc) * kW;

        const int i0 = q * 4;
        const int base = i0 + sx - R;      // multiple of 4 (R = sx & 3)
        int qa = base;       qa = qa < 0 ? 0 : qa; qa = qa > kW - 4 ? kW - 4 : qa;
        int qb = base + 4;   qb = qb < 0 ? 0 : qb; qb = qb > kW - 4 ? kW - 4 : qb;
        const float4 av = *(const float4*)(src + qa);
        const float4 bv = *(const float4*)(src + qb);
        const float* a = (const float*)&av;
        const float* b = (const float*)&bv;

        float sel[4];
        #pragma unroll
        for (int k = 0; k < 4; ++k)
            sel[k] = (k + R < 4) ? a[k + R] : b[k + R - 4];

        float4 o;
        float* po = (float*)&o;
        #pragma unroll
        for (int k = 0; k < 4; ++k) {
            const int s = i0 + k + sx;     // source column
            const float v = (rowok && (unsigned)s < (unsigned)kW) ? sel[k] : 0.0f;
            po[k] = (v - mn) * inv;
        }
        *(float4*)(ob + rr * kW + i0) = o; // 16B aligned
    }
}

__global__ __launch_bounds__(BLOCK) void shift_norm(
    const float* __restrict__ x, const float* __restrict__ sfy,
    const float* __restrict__ sfx, float* __restrict__ out)
{
    const int img = blockIdx.x;
    const float* __restrict__ xb = x + (size_t)img * kCHW;
    float* __restrict__ ob = out + (size_t)img * kCHW;

    // Replicate reference fp32 order: ((f*2-1)*0.1f)*size, trunc toward zero.
    float ty = sfy[img] * 2.0f - 1.0f; ty *= 0.1f; ty *= (float)kH;
    const int sy = (int)truncf(ty);
    float tx = sfx[img] * 2.0f - 1.0f; tx *= 0.1f; tx *= (float)kW;
    const int sx = (int)truncf(tx);

    const int tid = threadIdx.x;

    // Valid input sub-rectangle (rows/cols of x that survive the shift).
    const int rlo = sy > 0 ? sy : 0;
    const int rhi = kH + (sy < 0 ? sy : 0);
    const int clo = sx > 0 ? sx : 0;
    const int chi = kW + (sx < 0 ? sx : 0);

    float vmin = INFINITY, vmax = -INFINITY;

    // Phase 1: aligned float4 streaming min/max; invalid elements -> 0.
    for (int f = tid; f < kNQ; f += BLOCK) {
        const int rr = f / kQPR;
        const int q  = f - rr * kQPR;
        const int j  = rr % kH;
        const bool rok = (j >= rlo) & (j < rhi);
        const float4 v4 = *(const float4*)(xb + rr * kW + q * 4);
        const float* v = (const float*)&v4;
        #pragma unroll
        for (int k = 0; k < 4; ++k) {
            const int i = q * 4 + k;
            const float val = (rok & (i >= clo) & (i < chi)) ? v[k] : 0.0f;
            vmin = fminf(vmin, val);
            vmax = fmaxf(vmax, val);
        }
    }

    // Wave (64-lane) shuffle reduction, then cross-wave via LDS.
    #pragma unroll
    for (int off = 32; off > 0; off >>= 1) {
        vmin = fminf(vmin, __shfl_down(vmin, off));
        vmax = fmaxf(vmax, __shfl_down(vmax, off));
    }
    __shared__ float smin[BLOCK / 64], smax[BLOCK / 64];
    __shared__ float s_mn, s_inv;
    const int wave = tid >> 6, lane = tid & 63;
    if (lane == 0) { smin[wave] = vmin; smax[wave] = vmax; }
    __syncthreads();
    if (tid == 0) {
        float mn = smin[0], mx = smax[0];
        #pragma unroll
        for (int w2 = 1; w2 < BLOCK / 64; ++w2) {
            mn = fminf(mn, smin[w2]);
            mx = fmaxf(mx, smax[w2]);
        }
        s_mn = mn;
        s_inv = 1.0f / (mx - mn);
    }
    __syncthreads();
    const float mn = s_mn, inv = s_inv;

    // Phase 2: gather + normalize + aligned store; uniform rotate by sx&3.
    switch (sx & 3) {
        case 0: phase2<0>(xb, ob, sy, sx, mn, inv, tid); break;
        case 1: phase2<1>(xb, ob, sy, sx, mn, inv, tid); break;
        case 2: phase2<2>(xb, ob, sy, sx, mn, inv, tid); break;
        default: phase2<3>(xb, ob, sy, sx, mn, inv, tid); break;
    }
}

extern "C" void kernel_launch(void* const* d_in, const int* in_sizes, int n_in,
                              void* d_out, int out_size, void* d_ws, size_t ws_size,
                              hipStream_t stream) {
    const float* x  = (const float*)d_in[0];
    const float* fy = (const float*)d_in[1];
    const float* fx = (const float*)d_in[2];
    float* out = (float*)d_out;
    const int B = in_sizes[1];  // shift_fy has one element per image
    shift_norm<<<B, BLOCK, 0, stream>>>(x, fy, fx, out);
}